// Round 24
// baseline (90.053 us; speedup 1.0000x reference)
//
#include <hip/hip_runtime.h>
#include <hip/hip_bf16.h>
#include <math.h>

#define LOG2E 1.4426950408889634f
#define IS6   0.4082482904638630f

typedef _Float16 h2 __attribute__((ext_vector_type(2)));

#if defined(__has_builtin)
#if __has_builtin(__builtin_amdgcn_fdot2)
#define FDOT2(a,b,c) __builtin_amdgcn_fdot2((a),(b),(c),false)
#endif
#endif
#ifndef FDOT2
#define FDOT2(a,b,c) ((float)(a).x*(float)(b).x + (float)(a).y*(float)(b).y + (c))
#endif

__device__ __forceinline__ unsigned packh2(float x, float y) {
    h2 v; v.x = (_Float16)x; v.y = (_Float16)y;
    return *(unsigned*)&v;
}
__device__ __forceinline__ h2 ash2(unsigned u) { return *(h2*)&u; }
__device__ __forceinline__ unsigned ah2(h2 v) { return *(unsigned*)&v; }

__device__ __forceinline__ float fdot2_asm(h2 a, h2 b, float c) {
    float d;
    asm("v_dot2_f32_f16 %0, %1, %2, %3" : "=v"(d) : "v"(a), "v"(b), "v"(c));
    return d;
}
__device__ __forceinline__ float exp2_asm(float x) {
    float r;
    asm("v_exp_f32 %0, %1" : "=v"(r) : "v"(x));
    return r;
}

#if defined(__has_builtin)
#if __has_builtin(__builtin_amdgcn_cvt_pkrtz)
__device__ __forceinline__ h2 pk2(float a, float b) {
    auto r = __builtin_amdgcn_cvt_pkrtz(a, b);   // __fp16 ext_vector(2)
    union { decltype(r) f; h2 h; } c; c.f = r; return c.h;
}
#define HAVE_PK2 1
#endif
#endif
#ifndef HAVE_PK2
__device__ __forceinline__ h2 pk2(float a, float b) {
    h2 v; v.x = (_Float16)a; v.y = (_Float16)b; return v;
}
#endif

// ---------------- kernel 1: phi (blocks 0..511) + QKV (blocks 512..1663) ----------------
// NOTE: do NOT split phi into the rkS-LDS-staged kernel — R22 measured it at 107 us
// (VGPR 256, ~0% VALU, pathological codegen). The per-lane rk loads here are fine.
__global__ __launch_bounds__(256)
void k_pre(const float* __restrict__ x,
           const float* __restrict__ Wq, const float* __restrict__ Wk,
           const float* __restrict__ Wv,
           const float* __restrict__ bk, const float* __restrict__ bv,
           const float* __restrict__ rwb, const float* __restrict__ rrb,
           const float* __restrict__ rk,
           unsigned* __restrict__ QWt, unsigned* __restrict__ QRt,
           unsigned* __restrict__ Kpl, unsigned* __restrict__ Vpl,
           unsigned short* __restrict__ phiB) {
    __shared__ unsigned xs[64 * 97];        // 24832 B
    __shared__ uint4 Wlds[384];             // 6144 B
    __shared__ float rrowS[4 * 192];
    int tid = threadIdx.x;
    if (blockIdx.x < 512) {
        // ---- phi: 4 t per block ----
        int t0 = blockIdx.x * 4;
        for (int idx = tid; idx < 768; idx += 256) {
            int tl = idx / 192, d = idx - tl * 192;
            int dd = d < 96 ? d : d - 96;
            float w = exp2f(-(float)dd * 0.13841367062030676f);  // log2(10000)/96
            float ang = (float)(1024 - (t0 + tl)) * w;
            rrowS[idx] = (d < 96) ? __sinf(ang) : __cosf(ang);
        }
        __syncthreads();
        if (tid < 192) {
            int c = tid % 96, tg = tid / 96;
            float acc0 = 0.f, acc1 = 0.f;
            #pragma unroll 4
            for (int d = 0; d < 192; ++d) {
                float wv = rk[d * 96 + c];
                acc0 += rrowS[(tg * 2 + 0) * 192 + d] * wv;
                acc1 += rrowS[(tg * 2 + 1) * 192 + d] * wv;
            }
            int n = c / 6, h = c - n * 6;
            _Float16 v0 = (_Float16)acc0, v1 = (_Float16)acc1;
            phiB[(n * 2048 + t0 + tg * 2 + 0) * 8 + h] = *(unsigned short*)&v0;
            phiB[(n * 2048 + t0 + tg * 2 + 1) * 8 + h] = *(unsigned short*)&v1;
            if (tg == 0 && c < 32) {
                int nn = c >> 1, hh = 6 + (c & 1);
                #pragma unroll
                for (int k = 0; k < 4; ++k)
                    phiB[(nn * 2048 + t0 + k) * 8 + hh] = 0;
            }
        }
    } else {
        int qkvb = blockIdx.x - 512;
        int rt = qkvb / 18, qb = qkvb - rt * 18;
        int row0 = rt * 64;
        for (int idx = tid; idx < 6144; idx += 256) {
            int r = idx / 96, dpp = idx - r * 96;
            float2 xv = *(const float2*)&x[(size_t)(row0 + r) * 192 + dpp * 2];
            xs[r * 97 + dpp] = packh2(xv.x, xv.y);
        }
        for (int idx = tid; idx < 384; idx += 256) {
            int quad = idx / 96, dp = idx - quad * 96;
            int cq = qb * 4 + quad;
            int mat = cq / 24, c0 = (cq - mat * 24) * 4;
            const float* W = mat == 0 ? Wq : (mat == 1 ? Wk : Wv);
            float4 r0 = *(const float4*)&W[(2 * dp) * 96 + c0];
            float4 r1 = *(const float4*)&W[(2 * dp + 1) * 96 + c0];
            uint4 v;
            v.x = packh2(r0.x, r1.x);
            v.y = packh2(r0.y, r1.y);
            v.z = packh2(r0.z, r1.z);
            v.w = packh2(r0.w, r1.w);
            Wlds[idx] = v;
        }
        __syncthreads();
        int quad = __builtin_amdgcn_readfirstlane(tid >> 6);
        int sl = tid & 63;
        int cq = qb * 4 + quad;
        int c0g = cq * 4;
        int mat = c0g / 96, col0 = c0g - mat * 96;
        const uint4* wb = &Wlds[quad * 96];
        const unsigned* xr = xs + sl * 97;
        float a0 = 0.f, a1 = 0.f, a2 = 0.f, a3 = 0.f;
        #pragma unroll 8
        for (int dp = 0; dp < 96; ++dp) {
            uint4 w4 = wb[dp];
            h2 xp = ash2(xr[dp]);
            a0 = FDOT2(xp, ash2(w4.x), a0);
            a1 = FDOT2(xp, ash2(w4.y), a1);
            a2 = FDOT2(xp, ash2(w4.z), a2);
            a3 = FDOT2(xp, ash2(w4.w), a3);
        }
        float av[4] = {a0, a1, a2, a3};
        int row = row0 + sl, b = row >> 10, s = row & 1023;
        if (mat == 0) {
            #pragma unroll
            for (int pp = 0; pp < 2; ++pp) {
                int cA = col0 + 2 * pp;
                int pg = cA >> 1;
                int nn = pg / 3, hp = pg - nn * 3;
                int bnn = b * 16 + nn;
                unsigned qw = packh2((av[2*pp]   + rwb[cA])   * (IS6 * LOG2E),
                                     (av[2*pp+1] + rwb[cA+1]) * (IS6 * LOG2E));
                unsigned qr = packh2((av[2*pp]   + rrb[cA])   * (IS6 * LOG2E),
                                     (av[2*pp+1] + rrb[cA+1]) * (IS6 * LOG2E));
                size_t qo = ((size_t)(hp * 64 + bnn) << 10) + s;
                QWt[qo] = qw;
                QRt[qo] = qr;
            }
        } else if (mat == 1) {
            #pragma unroll
            for (int pp = 0; pp < 2; ++pp) {
                int cA = col0 + 2 * pp;
                int pg = cA >> 1;
                int nn = pg / 3, hp = pg - nn * 3;
                int bnn = b * 16 + nn;
                Kpl[((size_t)(hp * 64 + bnn) << 10) + s] =
                    packh2(av[2*pp] + bk[cA], av[2*pp+1] + bk[cA+1]);
            }
        } else {
            #pragma unroll
            for (int pp = 0; pp < 2; ++pp) {
                int cA = col0 + 2 * pp;
                int pg = cA >> 1;
                int nn = pg / 3, hp = pg - nn * 3;
                int bnn = b * 16 + nn;
                Vpl[((size_t)(hp * 64 + bnn) << 10) + s] =
                    packh2(av[2*pp] + bv[cA], av[2*pp+1] + bv[cA+1]);
            }
        }
    }
}

// ---------------- kernel 2: fused attention — 512 thr, 2 j-halves share phi staging ------
// grid (8 jc2, 16 n, 4 b) x 512 thr; half h = tid>>8 handles j in [jc2*128+64h, +64).
// Per-thread inner loop identical to R21/R23 (hand-unrolled, literal indices).
// phiS window = 1152 rows serves BOTH halves (staging per j halves vs 256-thr blocks).
// launch_bounds(512,4): 2 blocks/CU = 16 waves/CU, VGPR cap 128 (same as (256,4)).
#define SWZ(r) ((r) ^ (((r) >> 2) & 7))
__global__ __launch_bounds__(512, 4)
void k_attn(const unsigned* __restrict__ QWt, const unsigned* __restrict__ QRt,
            const unsigned* __restrict__ Kpl, const unsigned* __restrict__ Vpl,
            const float* __restrict__ mask0,
            const unsigned short* __restrict__ phiB,
            uint4* __restrict__ P) {
    __shared__ uint4 phiS[1152];    // 18432 B: rows j0+1 .. j0+1152
    __shared__ uint4 kS[129];       // 128 rows + [128] dummy for prefetch
    __shared__ uint4 vS[129];
    int tid = threadIdx.x;
    int jc2 = blockIdx.x, n = blockIdx.y, b = blockIdx.z;
    int j0 = jc2 * 128;
    int bn = b * 16 + n;
    int hh = tid >> 8;              // half 0/1
    int tid2 = tid & 255;

    const uint4* phg = (const uint4*)phiB + (n * 2048 + j0 + 1);
    for (int r = tid; r < 1152; r += 512) phiS[SWZ(r)] = phg[r];
    if (tid < 128) {
        int j = j0 + tid;
        size_t base = ((size_t)bn << 10) + j;
        float mt = 1e6f * (mask0[b * 1024 + j] - 1.0f) * LOG2E;
        kS[tid] = make_uint4(Kpl[base], Kpl[base + 65536], Kpl[base + 131072],
                             __float_as_uint(mt));
    } else if (tid < 256) {
        int r = tid - 128;
        int j = j0 + r;
        size_t base = ((size_t)bn << 10) + j;
        vS[r] = make_uint4(Vpl[base], Vpl[base + 65536], Vpl[base + 131072], 0u);
    } else if (tid == 256) {
        kS[128] = make_uint4(0u, 0u, 0u, 0u);
        vS[128] = make_uint4(0u, 0u, 0u, 0u);
    }
    __syncthreads();

    int iA = tid2 * 4;
    h2 qw[4][3], qr[4][3];
    #pragma unroll
    for (int hp = 0; hp < 3; ++hp) {
        size_t off = (size_t)hp * 65536 + ((size_t)bn << 10) + iA;
        uint4 qa = *(const uint4*)&QWt[off];
        qw[0][hp] = ash2(qa.x); qw[1][hp] = ash2(qa.y);
        qw[2][hp] = ash2(qa.z); qw[3][hp] = ash2(qa.w);
        uint4 ra = *(const uint4*)&QRt[off];
        qr[0][hp] = ash2(ra.x); qr[1][hp] = ash2(ra.y);
        qr[2][hp] = ash2(ra.z); qr[3][hp] = ash2(ra.w);
    }

    float den[4] = {0.f, 0.f, 0.f, 0.f};
    h2 zero2; zero2.x = (_Float16)0.f; zero2.y = (_Float16)0.f;
    h2 ac0[4], ac1[4], ac2[4];
    #pragma unroll
    for (int q = 0; q < 4; ++q) { ac0[q] = zero2; ac1[q] = zero2; ac2[q] = zero2; }

    int jb = hh * 64;               // this half's local j base within the 128-chunk
    int Cb = 1023 - iA + jb;        // local phi row for (q=0, local jj=0)
    uint4 ph[4];
    ph[3] = phiS[SWZ(Cb - 1)];
    ph[2] = phiS[SWZ(Cb - 2)];
    ph[1] = phiS[SWZ(Cb - 3)];
    uint4 nxt = phiS[SWZ(Cb)];
    uint4 Kc = kS[jb], Vc = vS[jb];

#define SCORE_AT(slot, qq)                                                      \
    {                                                                           \
        uint4 p = ph[slot];                                                     \
        float sc = fdot2_asm(ash2(K.x), qw[qq][0],                              \
                   fdot2_asm(ash2(K.y), qw[qq][1],                              \
                   fdot2_asm(ash2(K.z), qw[qq][2], mt)));                       \
        sc = fdot2_asm(ash2(p.x), qr[qq][0],                                    \
             fdot2_asm(ash2(p.y), qr[qq][1],                                    \
             fdot2_asm(ash2(p.z), qr[qq][2], sc)));                             \
        float e = exp2_asm(sc);                                                 \
        den[qq] += e;                                                           \
        h2 e2 = pk2(e, e);                                                      \
        ac0[qq] += e2 * v01;                                                    \
        ac1[qq] += e2 * v23;                                                    \
        ac2[qq] += e2 * v45;                                                    \
    }

#define STEP(kk, s0_, s1_, s2_, s3_)                                            \
    {                                                                           \
        const int jj = jb + j4 + (kk);                                          \
        uint4 K = Kc, V = Vc;                                                   \
        ph[kk] = nxt;                                                           \
        Kc = kS[jj + 1];                                                        \
        Vc = vS[jj + 1];                                                        \
        nxt = phiS[SWZ(Cb + j4 + (kk) + 1)];                                    \
        float mt = __uint_as_float(K.w);                                        \
        h2 v01 = ash2(V.x), v23 = ash2(V.y), v45 = ash2(V.z);                   \
        SCORE_AT(s0_, 0) SCORE_AT(s1_, 1) SCORE_AT(s2_, 2) SCORE_AT(s3_, 3)     \
    }

    for (int j4 = 0; j4 < 64; j4 += 4) {
        STEP(0, 0, 3, 2, 1)
        STEP(1, 1, 0, 3, 2)
        STEP(2, 2, 1, 0, 3)
        STEP(3, 3, 2, 1, 0)
    }
#undef STEP
#undef SCORE_AT

    int cidx = jc2 * 2 + hh;        // chunk index 0..15 (matches k_comb mapping)
    size_t pb = ((size_t)(cidx * 64 + bn)) << 10;
    #pragma unroll
    for (int q = 0; q < 4; ++q) {
        uint4 st;
        st.x = __float_as_uint(den[q]);
        st.y = ah2(ac0[q]); st.z = ah2(ac1[q]); st.w = ah2(ac2[q]);
        P[pb + q * 256 + tid2] = st;
    }
}

// ---------------- kernel 3: combine 16 chunks (fully coalesced) -> AV ----------------
__global__ __launch_bounds__(256)
void k_comb(const uint4* __restrict__ P, float* __restrict__ AV) {
    int flat = blockIdx.x * 256 + threadIdx.x;
    int bn = flat >> 10, rem = flat & 1023;
    int q = rem >> 8, tt = rem & 255;
    int i = tt * 4 + q;
    int b = bn >> 4, n = bn & 15;
    float d = 0.f, s0 = 0.f, s1 = 0.f, s2 = 0.f, s3 = 0.f, s4 = 0.f, s5 = 0.f;
    #pragma unroll
    for (int jc = 0; jc < 16; ++jc) {
        uint4 u = P[(((size_t)(jc * 64 + bn)) << 10) + rem];
        h2 x0 = ash2(u.y), x1 = ash2(u.z), x2 = ash2(u.w);
        d  += __uint_as_float(u.x);
        s0 += (float)x0.x; s1 += (float)x0.y;
        s2 += (float)x1.x; s3 += (float)x1.y;
        s4 += (float)x2.x; s5 += (float)x2.y;
    }
    float inv = 1.0f / d;
    float* o = AV + ((size_t)(b * 1024 + i)) * 96 + n * 6;
    o[0] = s0 * inv; o[1] = s1 * inv; o[2] = s2 * inv;
    o[3] = s3 * inv; o[4] = s4 * inv; o[5] = s5 * inv;
}

// ---------------- kernel 4: Wo projection + residual + LayerNorm ----------------
__global__ __launch_bounds__(256)
void k_out(const float* __restrict__ AV, const float* __restrict__ Wo,
           const float* __restrict__ bo, const float* __restrict__ x,
           const float* __restrict__ gamma, const float* __restrict__ beta,
           float* __restrict__ out) {
    __shared__ unsigned WoS[96 * 96];
    __shared__ float avS[8 * 96];
    int tid = threadIdx.x;
    int row0 = blockIdx.x * 8;
    for (int idx = tid; idx < 9216; idx += 256) {
        int c = idx / 96, pd = idx - c * 96;
        float2 w = *(const float2*)&Wo[c * 192 + pd * 2];
        WoS[idx] = packh2(w.x, w.y);
    }
    for (int idx = tid; idx < 768; idx += 256)
        avS[idx] = AV[(size_t)row0 * 96 + idx];
    __syncthreads();

    int lane = tid & 63, wv = tid >> 6;
    bool act = lane < 48;
    int d0 = lane * 4;
    #pragma unroll
    for (int rr = 0; rr < 2; ++rr) {
        int r = wv * 2 + rr, row = row0 + r;
        float ax = 0.f, ay = 0.f, az = 0.f, aw = 0.f;
        if (act) {
            float4 bq = *(const float4*)&bo[d0];
            float4 xq = *(const float4*)&x[(size_t)row * 192 + d0];
            ax = bq.x + xq.x; ay = bq.y + xq.y; az = bq.z + xq.z; aw = bq.w + xq.w;
            for (int c2 = 0; c2 < 96; ++c2) {
                float a = avS[r * 96 + c2];
                uint2 wp = *(uint2*)&WoS[c2 * 96 + lane * 2];
                h2 w0 = ash2(wp.x), w1 = ash2(wp.y);
                ax += a * (float)w0.x; ay += a * (float)w0.y;
                az += a * (float)w1.x; aw += a * (float)w1.y;
            }
        }
        float sum = act ? (ax + ay + az + aw) : 0.f;
        #pragma unroll
        for (int off = 32; off; off >>= 1) sum += __shfl_xor(sum, off, 64);
        float mu = sum * (1.0f / 192.0f);
        float dx = ax - mu, dy = ay - mu, dz = az - mu, dw = aw - mu;
        float vs = act ? (dx * dx + dy * dy + dz * dz + dw * dw) : 0.f;
        #pragma unroll
        for (int off = 32; off; off >>= 1) vs += __shfl_xor(vs, off, 64);
        float rstd = rsqrtf(vs * (1.0f / 192.0f) + 1e-9f);
        if (act) {
            float4 g = *(const float4*)&gamma[d0];
            float4 bb = *(const float4*)&beta[d0];
            float4 rv;
            rv.x = dx * rstd * g.x + bb.x;
            rv.y = dy * rstd * g.y + bb.y;
            rv.z = dz * rstd * g.z + bb.z;
            rv.w = dw * rstd * g.w + bb.w;
            *(float4*)&out[(size_t)row * 192 + d0] = rv;
        }
    }
}

// ---------------- launch ----------------
extern "C" void kernel_launch(void* const* d_in, const int* in_sizes, int n_in,
                              void* d_out, int out_size, void* d_ws, size_t ws_size,
                              hipStream_t stream) {
    const float* x        = (const float*)d_in[0];
    const float* mask0    = (const float*)d_in[1];
    const float* Wq       = (const float*)d_in[2];
    const float* Wk       = (const float*)d_in[3];
    const float* bk       = (const float*)d_in[4];
    const float* Wv       = (const float*)d_in[5];
    const float* bv       = (const float*)d_in[6];
    const float* Wo       = (const float*)d_in[7];
    const float* bo       = (const float*)d_in[8];
    const float* rwb      = (const float*)d_in[9];
    const float* rrb      = (const float*)d_in[10];
    const float* r_kernel = (const float*)d_in[11];
    const float* gamma    = (const float*)d_in[12];
    const float* beta     = (const float*)d_in[13];
    float* out = (float*)d_out;

    unsigned* QWt = (unsigned*)d_ws;                       // 196608 dwords
    unsigned* QRt = QWt + 196608;                          // 196608
    unsigned* Kpl = QRt + 196608;                          // 196608
    unsigned* Vpl = Kpl + 196608;                          // 196608
    uint4*    P   = (uint4*)(Vpl + 196608);                // 1048576 uint4 (16 MB)
    unsigned short* phiB = (unsigned short*)(P + 1048576); // 262144 ushorts
    float*    AV  = (float*)(phiB + 262144);               // 393216 floats

    k_pre<<<1664, 256, 0, stream>>>(x, Wq, Wk, Wv, bk, bv, rwb, rrb, r_kernel,
                                    QWt, QRt, Kpl, Vpl, phiB);
    k_attn<<<dim3(8, 16, 4), 512, 0, stream>>>(QWt, QRt, Kpl, Vpl, mask0, phiB, P);
    k_comb<<<256, 256, 0, stream>>>(P, AV);
    k_out<<<512, 256, 0, stream>>>(AV, Wo, bo, x, gamma, beta, out);
}

// Round 25
// 88.103 us; speedup vs baseline: 1.0221x; 1.0221x over previous
//
#include <hip/hip_runtime.h>
#include <hip/hip_bf16.h>
#include <math.h>

#define LOG2E 1.4426950408889634f
#define IS6   0.4082482904638630f

typedef _Float16 h2 __attribute__((ext_vector_type(2)));

#if defined(__has_builtin)
#if __has_builtin(__builtin_amdgcn_fdot2)
#define FDOT2(a,b,c) __builtin_amdgcn_fdot2((a),(b),(c),false)
#endif
#endif
#ifndef FDOT2
#define FDOT2(a,b,c) ((float)(a).x*(float)(b).x + (float)(a).y*(float)(b).y + (c))
#endif

__device__ __forceinline__ unsigned packh2(float x, float y) {
    h2 v; v.x = (_Float16)x; v.y = (_Float16)y;
    return *(unsigned*)&v;
}
__device__ __forceinline__ h2 ash2(unsigned u) { return *(h2*)&u; }
__device__ __forceinline__ unsigned ah2(h2 v) { return *(unsigned*)&v; }

__device__ __forceinline__ float fdot2_asm(h2 a, h2 b, float c) {
    float d;
    asm("v_dot2_f32_f16 %0, %1, %2, %3" : "=v"(d) : "v"(a), "v"(b), "v"(c));
    return d;
}
__device__ __forceinline__ float exp2_asm(float x) {
    float r;
    asm("v_exp_f32 %0, %1" : "=v"(r) : "v"(x));
    return r;
}

#if defined(__has_builtin)
#if __has_builtin(__builtin_amdgcn_cvt_pkrtz)
__device__ __forceinline__ h2 pk2(float a, float b) {
    auto r = __builtin_amdgcn_cvt_pkrtz(a, b);   // __fp16 ext_vector(2)
    union { decltype(r) f; h2 h; } c; c.f = r; return c.h;
}
#define HAVE_PK2 1
#endif
#endif
#ifndef HAVE_PK2
__device__ __forceinline__ h2 pk2(float a, float b) {
    h2 v; v.x = (_Float16)a; v.y = (_Float16)b; return v;
}
#endif

// ---------------- kernel 1: phi (blocks 0..511) + QKV (blocks 512..1663) ----------------
// NOTE: do NOT split phi into the rkS-LDS-staged kernel — R22 measured it at 107 us
// (VGPR 256, ~0% VALU, pathological codegen). The per-lane rk loads here are fine.
__global__ __launch_bounds__(256)
void k_pre(const float* __restrict__ x,
           const float* __restrict__ Wq, const float* __restrict__ Wk,
           const float* __restrict__ Wv,
           const float* __restrict__ bk, const float* __restrict__ bv,
           const float* __restrict__ rwb, const float* __restrict__ rrb,
           const float* __restrict__ rk,
           unsigned* __restrict__ QWt, unsigned* __restrict__ QRt,
           unsigned* __restrict__ Kpl, unsigned* __restrict__ Vpl,
           unsigned short* __restrict__ phiB) {
    __shared__ unsigned xs[64 * 97];        // 24832 B
    __shared__ uint4 Wlds[384];             // 6144 B
    __shared__ float rrowS[4 * 192];
    int tid = threadIdx.x;
    if (blockIdx.x < 512) {
        // ---- phi: 4 t per block ----
        int t0 = blockIdx.x * 4;
        for (int idx = tid; idx < 768; idx += 256) {
            int tl = idx / 192, d = idx - tl * 192;
            int dd = d < 96 ? d : d - 96;
            float w = exp2f(-(float)dd * 0.13841367062030676f);  // log2(10000)/96
            float ang = (float)(1024 - (t0 + tl)) * w;
            rrowS[idx] = (d < 96) ? __sinf(ang) : __cosf(ang);
        }
        __syncthreads();
        if (tid < 192) {
            int c = tid % 96, tg = tid / 96;
            float acc0 = 0.f, acc1 = 0.f;
            #pragma unroll 8
            for (int d = 0; d < 192; ++d) {
                float wv = rk[d * 96 + c];
                acc0 += rrowS[(tg * 2 + 0) * 192 + d] * wv;
                acc1 += rrowS[(tg * 2 + 1) * 192 + d] * wv;
            }
            int n = c / 6, h = c - n * 6;
            _Float16 v0 = (_Float16)acc0, v1 = (_Float16)acc1;
            phiB[(n * 2048 + t0 + tg * 2 + 0) * 8 + h] = *(unsigned short*)&v0;
            phiB[(n * 2048 + t0 + tg * 2 + 1) * 8 + h] = *(unsigned short*)&v1;
            if (tg == 0 && c < 32) {
                int nn = c >> 1, hh = 6 + (c & 1);
                #pragma unroll
                for (int k = 0; k < 4; ++k)
                    phiB[(nn * 2048 + t0 + k) * 8 + hh] = 0;
            }
        }
    } else {
        int qkvb = blockIdx.x - 512;
        int rt = qkvb / 18, qb = qkvb - rt * 18;
        int row0 = rt * 64;
        for (int idx = tid; idx < 6144; idx += 256) {
            int r = idx / 96, dpp = idx - r * 96;
            float2 xv = *(const float2*)&x[(size_t)(row0 + r) * 192 + dpp * 2];
            xs[r * 97 + dpp] = packh2(xv.x, xv.y);
        }
        for (int idx = tid; idx < 384; idx += 256) {
            int quad = idx / 96, dp = idx - quad * 96;
            int cq = qb * 4 + quad;
            int mat = cq / 24, c0 = (cq - mat * 24) * 4;
            const float* W = mat == 0 ? Wq : (mat == 1 ? Wk : Wv);
            float4 r0 = *(const float4*)&W[(2 * dp) * 96 + c0];
            float4 r1 = *(const float4*)&W[(2 * dp + 1) * 96 + c0];
            uint4 v;
            v.x = packh2(r0.x, r1.x);
            v.y = packh2(r0.y, r1.y);
            v.z = packh2(r0.z, r1.z);
            v.w = packh2(r0.w, r1.w);
            Wlds[idx] = v;
        }
        __syncthreads();
        int quad = __builtin_amdgcn_readfirstlane(tid >> 6);
        int sl = tid & 63;
        int cq = qb * 4 + quad;
        int c0g = cq * 4;
        int mat = c0g / 96, col0 = c0g - mat * 96;
        const uint4* wb = &Wlds[quad * 96];
        const unsigned* xr = xs + sl * 97;
        float a0 = 0.f, a1 = 0.f, a2 = 0.f, a3 = 0.f;
        #pragma unroll 8
        for (int dp = 0; dp < 96; ++dp) {
            uint4 w4 = wb[dp];
            h2 xp = ash2(xr[dp]);
            a0 = FDOT2(xp, ash2(w4.x), a0);
            a1 = FDOT2(xp, ash2(w4.y), a1);
            a2 = FDOT2(xp, ash2(w4.z), a2);
            a3 = FDOT2(xp, ash2(w4.w), a3);
        }
        float av[4] = {a0, a1, a2, a3};
        int row = row0 + sl, b = row >> 10, s = row & 1023;
        if (mat == 0) {
            #pragma unroll
            for (int pp = 0; pp < 2; ++pp) {
                int cA = col0 + 2 * pp;
                int pg = cA >> 1;
                int nn = pg / 3, hp = pg - nn * 3;
                int bnn = b * 16 + nn;
                unsigned qw = packh2((av[2*pp]   + rwb[cA])   * (IS6 * LOG2E),
                                     (av[2*pp+1] + rwb[cA+1]) * (IS6 * LOG2E));
                unsigned qr = packh2((av[2*pp]   + rrb[cA])   * (IS6 * LOG2E),
                                     (av[2*pp+1] + rrb[cA+1]) * (IS6 * LOG2E));
                size_t qo = ((size_t)(hp * 64 + bnn) << 10) + s;
                QWt[qo] = qw;
                QRt[qo] = qr;
            }
        } else if (mat == 1) {
            #pragma unroll
            for (int pp = 0; pp < 2; ++pp) {
                int cA = col0 + 2 * pp;
                int pg = cA >> 1;
                int nn = pg / 3, hp = pg - nn * 3;
                int bnn = b * 16 + nn;
                Kpl[((size_t)(hp * 64 + bnn) << 10) + s] =
                    packh2(av[2*pp] + bk[cA], av[2*pp+1] + bk[cA+1]);
            }
        } else {
            #pragma unroll
            for (int pp = 0; pp < 2; ++pp) {
                int cA = col0 + 2 * pp;
                int pg = cA >> 1;
                int nn = pg / 3, hp = pg - nn * 3;
                int bnn = b * 16 + nn;
                Vpl[((size_t)(hp * 64 + bnn) << 10) + s] =
                    packh2(av[2*pp] + bv[cA], av[2*pp+1] + bv[cA+1]);
            }
        }
    }
}

// ---------------- kernel 2: fused attention — HAND-UNROLLED, all indices literal ----------
// grid (16 jc, 16 n, 4 b) x 256 thr; thread = 4 ADJACENT queries; 64 j per block.
// launch_bounds(256,4) — (256,8) caps VGPR at 64 -> scratch (R16).
// SWZ(r) = r ^ ((r>>2)&7): conflict-free for lane row-stride 4 (R15 derivation).
#define SWZ(r) ((r) ^ (((r) >> 2) & 7))
__global__ __launch_bounds__(256, 4)
void k_attn(const unsigned* __restrict__ QWt, const unsigned* __restrict__ QRt,
            const unsigned* __restrict__ Kpl, const unsigned* __restrict__ Vpl,
            const float* __restrict__ mask0,
            const unsigned short* __restrict__ phiB,
            uint4* __restrict__ P) {
    __shared__ uint4 phiS[1088];
    __shared__ uint4 kS[65];        // [64] = dummy for prefetch
    __shared__ uint4 vS[65];
    int tid = threadIdx.x;
    int jc = blockIdx.x, n = blockIdx.y, b = blockIdx.z;
    int j0 = jc * 64;
    int bn = b * 16 + n;

    const uint4* phg = (const uint4*)phiB + (n * 2048 + j0 + 1);
    for (int r = tid; r < 1088; r += 256) phiS[SWZ(r)] = phg[r];
    if (tid < 64) {
        int j = j0 + tid;
        size_t base = ((size_t)bn << 10) + j;
        float mt = 1e6f * (mask0[b * 1024 + j] - 1.0f) * LOG2E;
        kS[tid] = make_uint4(Kpl[base], Kpl[base + 65536], Kpl[base + 131072],
                             __float_as_uint(mt));
    } else if (tid < 128) {
        int r = tid - 64;
        int j = j0 + r;
        size_t base = ((size_t)bn << 10) + j;
        vS[r] = make_uint4(Vpl[base], Vpl[base + 65536], Vpl[base + 131072], 0u);
    } else if (tid == 128) {
        kS[64] = make_uint4(0u, 0u, 0u, 0u);
        vS[64] = make_uint4(0u, 0u, 0u, 0u);
    }
    __syncthreads();

    int iA = tid * 4;
    h2 qw[4][3], qr[4][3];
    #pragma unroll
    for (int hp = 0; hp < 3; ++hp) {
        size_t off = (size_t)hp * 65536 + ((size_t)bn << 10) + iA;
        uint4 qa = *(const uint4*)&QWt[off];
        qw[0][hp] = ash2(qa.x); qw[1][hp] = ash2(qa.y);
        qw[2][hp] = ash2(qa.z); qw[3][hp] = ash2(qa.w);
        uint4 ra = *(const uint4*)&QRt[off];
        qr[0][hp] = ash2(ra.x); qr[1][hp] = ash2(ra.y);
        qr[2][hp] = ash2(ra.z); qr[3][hp] = ash2(ra.w);
    }

    float den[4] = {0.f, 0.f, 0.f, 0.f};
    h2 zero2; zero2.x = (_Float16)0.f; zero2.y = (_Float16)0.f;
    h2 ac0[4], ac1[4], ac2[4];
    #pragma unroll
    for (int q = 0; q < 4; ++q) { ac0[q] = zero2; ac1[q] = zero2; ac2[q] = zero2; }

    int Cb = 1023 - iA;
    uint4 ph[4];
    ph[3] = phiS[SWZ(Cb - 1)];
    ph[2] = phiS[SWZ(Cb - 2)];
    ph[1] = phiS[SWZ(Cb - 3)];
    uint4 nxt = phiS[SWZ(Cb)];
    uint4 Kc = kS[0], Vc = vS[0];

#define SCORE_AT(slot, qq)                                                      \
    {                                                                           \
        uint4 p = ph[slot];                                                     \
        float sc = fdot2_asm(ash2(K.x), qw[qq][0],                              \
                   fdot2_asm(ash2(K.y), qw[qq][1],                              \
                   fdot2_asm(ash2(K.z), qw[qq][2], mt)));                       \
        sc = fdot2_asm(ash2(p.x), qr[qq][0],                                    \
             fdot2_asm(ash2(p.y), qr[qq][1],                                    \
             fdot2_asm(ash2(p.z), qr[qq][2], sc)));                             \
        float e = exp2_asm(sc);                                                 \
        den[qq] += e;                                                           \
        h2 e2 = pk2(e, e);                                                      \
        ac0[qq] += e2 * v01;                                                    \
        ac1[qq] += e2 * v23;                                                    \
        ac2[qq] += e2 * v45;                                                    \
    }

#define STEP(kk, s0_, s1_, s2_, s3_)                                            \
    {                                                                           \
        const int jj = j4 + (kk);                                               \
        uint4 K = Kc, V = Vc;                                                   \
        ph[kk] = nxt;                                                           \
        Kc = kS[jj + 1];                                                        \
        Vc = vS[jj + 1];                                                        \
        nxt = phiS[SWZ(Cb + jj + 1)];                                           \
        float mt = __uint_as_float(K.w);                                        \
        h2 v01 = ash2(V.x), v23 = ash2(V.y), v45 = ash2(V.z);                   \
        SCORE_AT(s0_, 0) SCORE_AT(s1_, 1) SCORE_AT(s2_, 2) SCORE_AT(s3_, 3)     \
    }

    for (int j4 = 0; j4 < 64; j4 += 4) {
        STEP(0, 0, 3, 2, 1)
        STEP(1, 1, 0, 3, 2)
        STEP(2, 2, 1, 0, 3)
        STEP(3, 3, 2, 1, 0)
    }
#undef STEP
#undef SCORE_AT

    size_t pb = ((size_t)(jc * 64 + bn)) << 10;
    #pragma unroll
    for (int q = 0; q < 4; ++q) {
        uint4 st;
        st.x = __float_as_uint(den[q]);
        st.y = ah2(ac0[q]); st.z = ah2(ac1[q]); st.w = ah2(ac2[q]);
        P[pb + q * 256 + tid] = st;
    }
}

// ---------------- kernel 3: combine 16 chunks (fully coalesced) -> AV ----------------
__global__ __launch_bounds__(256)
void k_comb(const uint4* __restrict__ P, float* __restrict__ AV) {
    int flat = blockIdx.x * 256 + threadIdx.x;
    int bn = flat >> 10, rem = flat & 1023;
    int q = rem >> 8, tt = rem & 255;
    int i = tt * 4 + q;
    int b = bn >> 4, n = bn & 15;
    float d = 0.f, s0 = 0.f, s1 = 0.f, s2 = 0.f, s3 = 0.f, s4 = 0.f, s5 = 0.f;
    #pragma unroll
    for (int jc = 0; jc < 16; ++jc) {
        uint4 u = P[(((size_t)(jc * 64 + bn)) << 10) + rem];
        h2 x0 = ash2(u.y), x1 = ash2(u.z), x2 = ash2(u.w);
        d  += __uint_as_float(u.x);
        s0 += (float)x0.x; s1 += (float)x0.y;
        s2 += (float)x1.x; s3 += (float)x1.y;
        s4 += (float)x2.x; s5 += (float)x2.y;
    }
    float inv = 1.0f / d;
    float* o = AV + ((size_t)(b * 1024 + i)) * 96 + n * 6;
    o[0] = s0 * inv; o[1] = s1 * inv; o[2] = s2 * inv;
    o[3] = s3 * inv; o[4] = s4 * inv; o[5] = s5 * inv;
}

// ---------------- kernel 4: Wo projection + residual + LayerNorm ----------------
__global__ __launch_bounds__(256)
void k_out(const float* __restrict__ AV, const float* __restrict__ Wo,
           const float* __restrict__ bo, const float* __restrict__ x,
           const float* __restrict__ gamma, const float* __restrict__ beta,
           float* __restrict__ out) {
    __shared__ unsigned WoS[96 * 96];
    __shared__ float avS[8 * 96];
    int tid = threadIdx.x;
    int row0 = blockIdx.x * 8;
    for (int idx = tid; idx < 9216; idx += 256) {
        int c = idx / 96, pd = idx - c * 96;
        float2 w = *(const float2*)&Wo[c * 192 + pd * 2];
        WoS[idx] = packh2(w.x, w.y);
    }
    for (int idx = tid; idx < 768; idx += 256)
        avS[idx] = AV[(size_t)row0 * 96 + idx];
    __syncthreads();

    int lane = tid & 63, wv = tid >> 6;
    bool act = lane < 48;
    int d0 = lane * 4;
    #pragma unroll
    for (int rr = 0; rr < 2; ++rr) {
        int r = wv * 2 + rr, row = row0 + r;
        float ax = 0.f, ay = 0.f, az = 0.f, aw = 0.f;
        if (act) {
            float4 bq = *(const float4*)&bo[d0];
            float4 xq = *(const float4*)&x[(size_t)row * 192 + d0];
            ax = bq.x + xq.x; ay = bq.y + xq.y; az = bq.z + xq.z; aw = bq.w + xq.w;
            for (int c2 = 0; c2 < 96; ++c2) {
                float a = avS[r * 96 + c2];
                uint2 wp = *(uint2*)&WoS[c2 * 96 + lane * 2];
                h2 w0 = ash2(wp.x), w1 = ash2(wp.y);
                ax += a * (float)w0.x; ay += a * (float)w0.y;
                az += a * (float)w1.x; aw += a * (float)w1.y;
            }
        }
        float sum = act ? (ax + ay + az + aw) : 0.f;
        #pragma unroll
        for (int off = 32; off; off >>= 1) sum += __shfl_xor(sum, off, 64);
        float mu = sum * (1.0f / 192.0f);
        float dx = ax - mu, dy = ay - mu, dz = az - mu, dw = aw - mu;
        float vs = act ? (dx * dx + dy * dy + dz * dz + dw * dw) : 0.f;
        #pragma unroll
        for (int off = 32; off; off >>= 1) vs += __shfl_xor(vs, off, 64);
        float rstd = rsqrtf(vs * (1.0f / 192.0f) + 1e-9f);
        if (act) {
            float4 g = *(const float4*)&gamma[d0];
            float4 bb = *(const float4*)&beta[d0];
            float4 rv;
            rv.x = dx * rstd * g.x + bb.x;
            rv.y = dy * rstd * g.y + bb.y;
            rv.z = dz * rstd * g.z + bb.z;
            rv.w = dw * rstd * g.w + bb.w;
            *(float4*)&out[(size_t)row * 192 + d0] = rv;
        }
    }
}

// ---------------- launch ----------------
extern "C" void kernel_launch(void* const* d_in, const int* in_sizes, int n_in,
                              void* d_out, int out_size, void* d_ws, size_t ws_size,
                              hipStream_t stream) {
    const float* x        = (const float*)d_in[0];
    const float* mask0    = (const float*)d_in[1];
    const float* Wq       = (const float*)d_in[2];
    const float* Wk       = (const float*)d_in[3];
    const float* bk       = (const float*)d_in[4];
    const float* Wv       = (const float*)d_in[5];
    const float* bv       = (const float*)d_in[6];
    const float* Wo       = (const float*)d_in[7];
    const float* bo       = (const float*)d_in[8];
    const float* rwb      = (const float*)d_in[9];
    const float* rrb      = (const float*)d_in[10];
    const float* r_kernel = (const float*)d_in[11];
    const float* gamma    = (const float*)d_in[12];
    const float* beta     = (const float*)d_in[13];
    float* out = (float*)d_out;

    unsigned* QWt = (unsigned*)d_ws;                       // 196608 dwords
    unsigned* QRt = QWt + 196608;                          // 196608
    unsigned* Kpl = QRt + 196608;                          // 196608
    unsigned* Vpl = Kpl + 196608;                          // 196608
    uint4*    P   = (uint4*)(Vpl + 196608);                // 1048576 uint4 (16 MB)
    unsigned short* phiB = (unsigned short*)(P + 1048576); // 262144 ushorts
    float*    AV  = (float*)(phiB + 262144);               // 393216 floats

    k_pre<<<1664, 256, 0, stream>>>(x, Wq, Wk, Wv, bk, bv, rwb, rrb, r_kernel,
                                    QWt, QRt, Kpl, Vpl, phiB);
    k_attn<<<dim3(16, 16, 4), 256, 0, stream>>>(QWt, QRt, Kpl, Vpl, mask0, phiB, P);
    k_comb<<<256, 256, 0, stream>>>(P, AV);
    k_out<<<512, 256, 0, stream>>>(AV, Wo, bo, x, gamma, beta, out);
}